// Round 1
// baseline (620.379 us; speedup 1.0000x reference)
//
#include <hip/hip_runtime.h>
#include <math.h>

// Problem constants (fixed by reference): F=64, D=32, NB=64, NUM=4.
// N, E taken from in_sizes for robustness.
#define F_DIM 64
#define D_DIM 32
#define NB_ROWS 64
#define NUM_S 4

// ws layout (floats):
//   [0 .. 4096)          : M table, M[b][f] = sum_d embed[b][d]*G_w[f][d]   (16 KB)
//   [4096 .. 4096+N)     : d0  (in-degree  based, from dst)
//   [4096+N .. 4096+2N)  : d2  (out-degree based, from src)
// total: (4096 + 2*50000)*4 B ~= 416 KB

__global__ void m_table_kernel(const float* __restrict__ embed,
                               const float* __restrict__ G_w,
                               float* __restrict__ M) {
    // grid: 64 blocks x 64 threads. block b computes M[b][f], f = threadIdx.x
    int b = blockIdx.x;
    int f = threadIdx.x;
    float acc = 0.f;
    #pragma unroll
    for (int d = 0; d < D_DIM; ++d)
        acc += embed[b * D_DIM + d] * G_w[f * D_DIM + d];
    M[b * F_DIM + f] = acc;
}

__global__ void deg_kernel(const int* __restrict__ src, const int* __restrict__ dst,
                           float* __restrict__ d0, float* __restrict__ d2, int E) {
    int i = blockIdx.x * blockDim.x + threadIdx.x;
    if (i < E) {
        atomicAdd(&d0[dst[i]], 1.0f);   // in-degree
        atomicAdd(&d2[src[i]], 1.0f);   // out-degree
    }
}

__global__ void deg_transform_kernel(float* __restrict__ d0, float* __restrict__ d2, int N) {
    int i = blockIdx.x * blockDim.x + threadIdx.x;
    if (i < N) {
        d0[i] = 1.0f / sqrtf(fmaxf(d0[i], 1.0f));
        d2[i] = 1.0f / sqrtf(fmaxf(d2[i], 1.0f));
    }
}

__global__ __launch_bounds__(256) void edge_kernel(
    const float* __restrict__ feat, const float* __restrict__ loc,
    const float* __restrict__ boundaries, const float* __restrict__ agg_w,
    const float* __restrict__ agg_b, const int* __restrict__ src,
    const int* __restrict__ dst, const int* __restrict__ inter,
    const float* __restrict__ M, const float* __restrict__ d0,
    const float* __restrict__ d2, float* __restrict__ out, int E) {

    __shared__ float cat[4][128];   // per-wave cat vector
    const int lane = threadIdx.x & 63;
    const int wid  = threadIdx.x >> 6;

    // Preload this lane's agg_w row into registers: ar[k] = agg_w[lane][k], k<128.
    float ar[128];
    const float4* awv = (const float4*)(agg_w + lane * 128);
    #pragma unroll
    for (int i = 0; i < 32; ++i) ((float4*)ar)[i] = awv[i];
    const float bias = agg_b[lane];
    // boundaries in a register: lane holds boundaries[lane] (63 real, lane63 = +inf)
    const float bnd = (lane < 63) ? boundaries[lane] : 3.4e38f;

    const int gwave = blockIdx.x * 4 + wid;
    const int nwaves = gridDim.x * 4;

    for (int e = gwave; e < E; e += nwaves) {
        const int s = src[e];
        const int d = dst[e];
        const int4 ii = *(const int4*)(inter + e * 4);

        const float sx = loc[s * 3 + 0], sy = loc[s * 3 + 1], sz = loc[s * 3 + 2];

        // dist(dst, src) -> bucket b1 (wave-uniform; ballot over per-lane boundary)
        float dx = loc[d * 3 + 0] - sx, dy = loc[d * 3 + 1] - sy, dz = loc[d * 3 + 2] - sz;
        float dist1 = sqrtf(dx * dx + dy * dy + dz * dz);
        int b1 = (int)__popcll(__ballot(bnd < dist1));

        float c1 = M[b1 * F_DIM + lane] * feat[s * F_DIM + lane];

        float c2 = 0.f;
        const int idx[4] = {ii.x, ii.y, ii.z, ii.w};
        #pragma unroll
        for (int j = 0; j < NUM_S; ++j) {
            int t = idx[j];
            float tx = loc[t * 3 + 0] - sx, ty = loc[t * 3 + 1] - sy, tz = loc[t * 3 + 2] - sz;
            float dj = sqrtf(tx * tx + ty * ty + tz * tz);
            int bj = (int)__popcll(__ballot(bnd < dj));
            c2 += M[bj * F_DIM + lane] * feat[t * F_DIM + lane];
        }
        c2 *= 0.25f;

        // stage cat through LDS (same-wave write->read; compiler inserts lgkmcnt wait)
        cat[wid][lane] = c1;
        cat[wid][64 + lane] = c2;

        float msg = bias;
        #pragma unroll
        for (int k4 = 0; k4 < 32; ++k4) {
            float4 c = ((const float4*)cat[wid])[k4];   // broadcast read
            msg += ar[k4 * 4 + 0] * c.x;
            msg += ar[k4 * 4 + 1] * c.y;
            msg += ar[k4 * 4 + 2] * c.z;
            msg += ar[k4 * 4 + 3] * c.w;
        }

        const float scale = d0[d] * d2[s];
        atomicAdd(&out[d * F_DIM + lane], scale * msg);
    }
}

extern "C" void kernel_launch(void* const* d_in, const int* in_sizes, int n_in,
                              void* d_out, int out_size, void* d_ws, size_t ws_size,
                              hipStream_t stream) {
    const float* feat       = (const float*)d_in[0];
    const float* loc        = (const float*)d_in[1];
    const float* boundaries = (const float*)d_in[2];
    const float* embed      = (const float*)d_in[3];
    const float* G_w        = (const float*)d_in[4];
    const float* agg_w      = (const float*)d_in[5];
    const float* agg_b      = (const float*)d_in[6];
    const int*   src        = (const int*)d_in[7];
    const int*   dst        = (const int*)d_in[8];
    const int*   inter      = (const int*)d_in[9];

    const int N = in_sizes[0] / F_DIM;   // 50000
    const int E = in_sizes[7];           // 500000

    float* M  = (float*)d_ws;
    float* d0 = M + NB_ROWS * F_DIM;
    float* d2 = d0 + N;
    float* out = (float*)d_out;

    // zero output (harness poisons 0xAA) and degree accumulators
    hipMemsetAsync(out, 0, (size_t)N * F_DIM * sizeof(float), stream);
    hipMemsetAsync(d0, 0, (size_t)2 * N * sizeof(float), stream);

    m_table_kernel<<<NB_ROWS, F_DIM, 0, stream>>>(embed, G_w, M);
    deg_kernel<<<(E + 255) / 256, 256, 0, stream>>>(src, dst, d0, d2, E);
    deg_transform_kernel<<<(N + 255) / 256, 256, 0, stream>>>(d0, d2, N);
    edge_kernel<<<2048, 256, 0, stream>>>(feat, loc, boundaries, agg_w, agg_b,
                                          src, dst, inter, M, d0, d2, out, E);
}